// Round 1
// baseline (1294.946 us; speedup 1.0000x reference)
//
#include <hip/hip_runtime.h>

// Problem constants
#define N_TH   4609      // D_THETA
#define PSTR   4624      // padded column stride (floats), 16B-aligned
#define TSTR   4624      // theta_outs row stride (floats)
#define NB     32        // BATCH
#define NL     32        // L
#define IND    10        // IN_DIM

// ws layout (float offsets):
//   du    : [0, 10240)
//   Pf    : [16384, 16384 + 33*11*PSTR)        Krylov blocks P_k, k=0..32, layout [k][c][i]
//   theta : [1694896, 1694896 + 1024*TSTR)     theta_outs, layout [bt][i]
#define WS_DU     0
#define WS_PF     16384
#define WS_THETA  1694896

// ---------------------------------------------------------------------------
// du[b][t][d] = u(b,t,d) - u(b,t-1,d), du[:,0,:] = 0 ; u = [ts, xs]
__global__ __launch_bounds__(256) void k_du(const float* __restrict__ xs,
                                            const float* __restrict__ ts,
                                            float* __restrict__ du) {
    int idx = blockIdx.x * 256 + threadIdx.x;
    if (idx >= NB * NL * IND) return;
    int d  = idx % IND;
    int bt = idx / IND;
    int t = bt % NL, b = bt / NL;
    if (t == 0) { du[idx] = 0.f; return; }
    float cur  = (d == 0) ? ts[b * NL + t]     : xs[(b * NL + t) * 9 + (d - 1)];
    float prev = (d == 0) ? ts[b * NL + t - 1] : xs[(b * NL + t - 1) * 9 + (d - 1)];
    du[idx] = cur - prev;
}

// ---------------------------------------------------------------------------
// P_0 = [theta0 | B], stored column-major: Pf[c][i], c in [0,11)
__global__ __launch_bounds__(256) void k_p0(const float* __restrict__ theta0,
                                            const float* __restrict__ Bm,
                                            float* __restrict__ Pf) {
    int idx = blockIdx.x * 256 + threadIdx.x;
    if (idx >= 11 * N_TH) return;
    int c = idx / N_TH, i = idx % N_TH;
    float v = (c == 0) ? theta0[i] : Bm[i * 10 + (c - 1)];
    Pf[c * PSTR + i] = v;
}

// ---------------------------------------------------------------------------
// One scan step: Pout[c][i] = sum_j A[i][j] * Pin[c][j]
// grid 577 blocks; block = 256 thr = 4 waves. Block owns 8 output rows.
// Each wave handles a quarter of the K=4609 reduction; lanes stride j.
__global__ __launch_bounds__(256) void k_step(const float* __restrict__ A,
                                              const float* __restrict__ Pin,
                                              float* __restrict__ Pout) {
    __shared__ float red[4 * 88];
    const int tid  = threadIdx.x;
    const int lane = tid & 63;
    const int w    = tid >> 6;
    const int i0   = blockIdx.x * 8;

    const int jstart = w * 1153;
    int jend = jstart + 1153;
    if (jend > N_TH) jend = N_TH;

    // Clamped row bases (last block has rows past N_TH; loads clamped, stores predicated)
    int rowbase[8];
#pragma unroll
    for (int r = 0; r < 8; r++) {
        int ir = i0 + r;
        if (ir > N_TH - 1) ir = N_TH - 1;
        rowbase[r] = ir * N_TH;
    }

    float acc[8][11];
#pragma unroll
    for (int r = 0; r < 8; r++)
#pragma unroll
        for (int c = 0; c < 11; c++) acc[r][c] = 0.f;

    for (int j = jstart + lane; j < jend; j += 64) {
        float p[11];
#pragma unroll
        for (int c = 0; c < 11; c++) p[c] = Pin[c * PSTR + j];
        float a[8];
#pragma unroll
        for (int r = 0; r < 8; r++) a[r] = A[rowbase[r] + j];
#pragma unroll
        for (int r = 0; r < 8; r++)
#pragma unroll
            for (int c = 0; c < 11; c++)
                acc[r][c] = fmaf(a[r], p[c], acc[r][c]);
    }

    // in-wave butterfly reduce, then lane 0 deposits to LDS
#pragma unroll
    for (int r = 0; r < 8; r++)
#pragma unroll
        for (int c = 0; c < 11; c++) {
            float v = acc[r][c];
            v += __shfl_xor(v, 32);
            v += __shfl_xor(v, 16);
            v += __shfl_xor(v, 8);
            v += __shfl_xor(v, 4);
            v += __shfl_xor(v, 2);
            v += __shfl_xor(v, 1);
            if (lane == 0) red[w * 88 + r * 11 + c] = v;
        }
    __syncthreads();

    if (tid < 88) {
        int r = tid / 11, c = tid % 11;
        int i = i0 + r;
        if (i < N_TH) {
            float s = red[tid] + red[88 + tid] + red[176 + tid] + red[264 + tid];
            Pout[c * PSTR + i] = s;
        }
    }
}

// ---------------------------------------------------------------------------
// theta_outs[bt][i] = Pf[t+1][0][i] + sum_{j<t} sum_d Pf[j][1+d][i] * du[b][t-j][d]
// GEMM: M=1024 (bt), N=4609 (i), K=320 (j*10+d). Tiles: 32 bt x 128 i x 32 k.
__global__ __launch_bounds__(256) void k_conv(const float* __restrict__ du,
                                              const float* __restrict__ Pf,
                                              float* __restrict__ theta) {
    __shared__ float Cf[32][32];    // coef tile [m][k]
    __shared__ float Pl[32][128];   // P tile [k][i]
    const int tid = threadIdx.x;
    const int i0  = blockIdx.x * 128;
    const int bt0 = blockIdx.y * 32;
    const int tn = tid & 31;   // i-group
    const int tm = tid >> 5;   // bt-group (0..7)

    float acc[4][4];
#pragma unroll
    for (int m = 0; m < 4; m++)
#pragma unroll
        for (int n = 0; n < 4; n++) acc[m][n] = 0.f;

    for (int k0 = 0; k0 < 320; k0 += 32) {
        // stage coef tile (32 bt x 32 k), built on the fly from du
#pragma unroll
        for (int s = 0; s < 4; s++) {
            int idx = s * 256 + tid;
            int m = idx >> 5, kk = idx & 31;
            int k = k0 + kk;
            int j = k / 10, d = k - j * 10;
            int bt = bt0 + m, t = bt & 31, b = bt >> 5;
            float v = 0.f;
            if (j < t) v = du[(b * NL + (t - j)) * IND + d];
            Cf[m][kk] = v;
        }
        // stage P tile (32 k x 128 i)
#pragma unroll
        for (int s = 0; s < 16; s++) {
            int idx = s * 256 + tid;
            int kk = idx >> 7, ii = idx & 127;
            int k = k0 + kk;
            int j = k / 10, d = k - j * 10;
            int i = i0 + ii;
            float v = 0.f;
            if (i < N_TH) v = Pf[(j * 11 + 1 + d) * PSTR + i];
            Pl[kk][ii] = v;
        }
        __syncthreads();
#pragma unroll
        for (int kk = 0; kk < 32; kk++) {
            float a0 = Cf[tm * 4 + 0][kk];
            float a1 = Cf[tm * 4 + 1][kk];
            float a2 = Cf[tm * 4 + 2][kk];
            float a3 = Cf[tm * 4 + 3][kk];
            float4 bv = *(const float4*)&Pl[kk][tn * 4];
            acc[0][0] = fmaf(a0, bv.x, acc[0][0]);
            acc[0][1] = fmaf(a0, bv.y, acc[0][1]);
            acc[0][2] = fmaf(a0, bv.z, acc[0][2]);
            acc[0][3] = fmaf(a0, bv.w, acc[0][3]);
            acc[1][0] = fmaf(a1, bv.x, acc[1][0]);
            acc[1][1] = fmaf(a1, bv.y, acc[1][1]);
            acc[1][2] = fmaf(a1, bv.z, acc[1][2]);
            acc[1][3] = fmaf(a1, bv.w, acc[1][3]);
            acc[2][0] = fmaf(a2, bv.x, acc[2][0]);
            acc[2][1] = fmaf(a2, bv.y, acc[2][1]);
            acc[2][2] = fmaf(a2, bv.z, acc[2][2]);
            acc[2][3] = fmaf(a2, bv.w, acc[2][3]);
            acc[3][0] = fmaf(a3, bv.x, acc[3][0]);
            acc[3][1] = fmaf(a3, bv.y, acc[3][1]);
            acc[3][2] = fmaf(a3, bv.z, acc[3][2]);
            acc[3][3] = fmaf(a3, bv.w, acc[3][3]);
        }
        __syncthreads();
    }

    // epilogue: add bias column Pf[t+1][0][:] and store
#pragma unroll
    for (int m = 0; m < 4; m++) {
        int bt = bt0 + tm * 4 + m;
        int t = bt & 31;
        const float* bias = &Pf[((t + 1) * 11) * PSTR];
#pragma unroll
        for (int n = 0; n < 4; n++) {
            int i = i0 + tn * 4 + n;
            if (i < N_TH) theta[bt * TSTR + i] = acc[m][n] + bias[i];
        }
    }
}

// ---------------------------------------------------------------------------
// Hypernetwork MLP: one (b,t) per 32-lane half-wave; neuron o per lane.
__global__ __launch_bounds__(256) void k_mlp(const float* __restrict__ xs,
                                             const float* __restrict__ ts,
                                             const float* __restrict__ theta,
                                             float* __restrict__ out) {
    const int tid  = threadIdx.x;
    const int lane = tid & 63;
    const int half = (lane >> 5) & 1;
    const int o    = lane & 31;
    const int wv   = tid >> 6;
    const int bt   = blockIdx.x * 8 + wv * 2 + half;
    const int b = bt >> 5, t = bt & 31;
    const float* th = theta + bt * TSTR;

    float u[10];
    u[0] = ts[b * NL + t];
#pragma unroll
    for (int d = 0; d < 9; d++) u[1 + d] = xs[(b * NL + t) * 9 + d];

    // layer 1: W (32x10) @ u + b
    float acc = th[320 + o];
#pragma unroll
    for (int i = 0; i < 10; i++) acc = fmaf(th[o * 10 + i], u[i], acc);
    float h = fmaxf(acc, 0.f);

    // layers 2..5: W (32x32) @ h + b, relu
#pragma unroll
    for (int l = 0; l < 4; l++) {
        int base = 352 + l * 1056;
        float a2 = th[base + 1024 + o];
#pragma unroll
        for (int i = 0; i < 32; i++)
            a2 = fmaf(th[base + o * 32 + i], __shfl(h, i, 32), a2);
        h = fmaxf(a2, 0.f);
    }

    // final layer: (1x32) @ h + b
    float contrib = th[4576 + o] * h;
#pragma unroll
    for (int m = 16; m >= 1; m >>= 1) contrib += __shfl_xor(contrib, m, 32);
    if (o == 0) out[bt] = contrib + th[4608];
}

// ---------------------------------------------------------------------------
extern "C" void kernel_launch(void* const* d_in, const int* in_sizes, int n_in,
                              void* d_out, int out_size, void* d_ws, size_t ws_size,
                              hipStream_t stream) {
    const float* xs  = (const float*)d_in[0];
    const float* ts  = (const float*)d_in[1];
    const float* A   = (const float*)d_in[2];
    const float* Bm  = (const float*)d_in[3];
    const float* th0 = (const float*)d_in[4];
    float* out = (float*)d_out;
    float* ws  = (float*)d_ws;

    float* du    = ws + WS_DU;
    float* Pf    = ws + WS_PF;
    float* theta = ws + WS_THETA;

    k_du<<<40, 256, 0, stream>>>(xs, ts, du);
    k_p0<<<199, 256, 0, stream>>>(th0, Bm, Pf);

    for (int k = 1; k <= 32; k++) {
        k_step<<<577, 256, 0, stream>>>(A, Pf + (k - 1) * 11 * PSTR, Pf + k * 11 * PSTR);
    }

    dim3 cgrid(37, 32);
    k_conv<<<cgrid, 256, 0, stream>>>(du, Pf, theta);
    k_mlp<<<128, 256, 0, stream>>>(xs, ts, theta, out);
}

// Round 4
// 1240.023 us; speedup vs baseline: 1.0443x; 1.0443x over previous
//
#include <hip/hip_runtime.h>

// Problem constants
#define N_TH   4609      // D_THETA
#define NPAD   4864      // padded i-dim (38*128 = 19*256)
#define PRS    12        // Prow row stride (floats)
#define PCS    4612      // PcolX plane stride (floats, mult of 4)
#define TSTR   4612      // theta row stride (floats, mult of 4)
#define KB     16        // k-split (partial slices)
#define CHUNK  289       // j-chunk per split (16*289 >= 4609)
#define NB     32
#define NL     32
#define IND    10

// ws layout (float offsets) — sized to PROVEN-SAFE ws bound (25.66 MB Tier B)
#define OF_DU    0          // 10,240
#define OF_PROW  10240      // 58,368  (NPAD*12, in-place updated)
#define OF_PCOL  68608      // 1,623,424 (32 kplanes * 11 cols * 4612)
#define OF_PART  1692032    // 856,064 (KB*11*NPAD)
// Tier A: A2 (bf16, 19*4609*256 ushort = 11,208,832 float-equiv) at 2,548,096;
//         theta (1024*4612) aliases A2 start. Total A = 13,756,928 fl = 55.0 MB.
// Tier B: theta aliases part start. Total B = 6,414,720 fl = 25.66 MB.
#define OF_A2    2548096
#define TIER_A_FLOATS 13756928ULL

// ---------------------------------------------------------------------------
__global__ __launch_bounds__(256) void k_du(const float* __restrict__ xs,
                                            const float* __restrict__ ts,
                                            float* __restrict__ du) {
    int idx = blockIdx.x * 256 + threadIdx.x;
    if (idx >= NB * NL * IND) return;
    int d  = idx % IND;
    int bt = idx / IND;
    int t = bt % NL, b = bt / NL;
    if (t == 0) { du[idx] = 0.f; return; }
    float cur  = (d == 0) ? ts[b * NL + t]     : xs[(b * NL + t) * 9 + (d - 1)];
    float prev = (d == 0) ? ts[b * NL + t - 1] : xs[(b * NL + t - 1) * 9 + (d - 1)];
    du[idx] = cur - prev;
}

// ---------------------------------------------------------------------------
// P_0 = [theta0 | B] into Prow (stride 12) and PcolX kplane 0 cols 1..10.
__global__ __launch_bounds__(256) void k_p0(const float* __restrict__ th0,
                                            const float* __restrict__ Bm,
                                            float* __restrict__ Prow,
                                            float* __restrict__ PcolX) {
    int idx = blockIdx.x * 256 + threadIdx.x;   // over NPAD*12
    if (idx >= NPAD * PRS) return;
    int i = idx / PRS, c = idx - i * PRS;
    float v = 0.f;
    if (i < N_TH) {
        if (c == 0) v = th0[i];
        else if (c <= 10) v = Bm[(size_t)i * 10 + (c - 1)];
    }
    Prow[idx] = v;
    if (c >= 1 && c <= 10 && i < PCS)
        PcolX[(size_t)c * PCS + i] = v;   // kplane 0, col c
}

// ---------------------------------------------------------------------------
// Tier A only: A2[ib][j][iin] = bf16(A[i][j] - (i==j)), i = ib*256+iin.
__global__ __launch_bounds__(256) void k_tr(const float* __restrict__ A,
                                            unsigned short* __restrict__ A2) {
    __shared__ float T[64][65];
    const int tid = threadIdx.x;
    const int i0 = blockIdx.x * 64;   // 0..75
    const int j0 = blockIdx.y * 64;   // 0..72
#pragma unroll
    for (int e = 0; e < 16; e++) {
        int idx = e * 256 + tid;
        int r = idx >> 6, q = idx & 63;
        int i = i0 + r, j = j0 + q;
        float v = 0.f;
        if (i < N_TH && j < N_TH) {
            v = A[(size_t)i * N_TH + j];
            if (i == j) v -= 1.f;
        }
        T[r][q] = v;
    }
    __syncthreads();
#pragma unroll
    for (int e = 0; e < 16; e++) {
        int idx = e * 256 + tid;
        int jj = idx >> 6, ii = idx & 63;
        int j = j0 + jj;
        if (j < N_TH) {
            int i = i0 + ii;
            int ib = i >> 8, iin = i & 255;
            float v = T[ii][jj];
            unsigned int u = __float_as_uint(v);
            unsigned int rb = (u + 0x7fffu + ((u >> 16) & 1u)) >> 16;  // RNE
            A2[((size_t)ib * N_TH + j) * 256 + iin] = (unsigned short)rb;
        }
    }
}

// ---------------------------------------------------------------------------
// Tier A step: part[bx][c][i] += over j-chunk of bf16 (A-I)^T * P.
// grid (KB, 38); lanes own 2 i; waves split chunk 4-way; LDS reduce.
__global__ __launch_bounds__(256) void k_stepA(const unsigned short* __restrict__ A2,
                                               const float* __restrict__ Prow,
                                               float* __restrict__ part) {
    __shared__ float red[3 * 22 * 64];
    const int tid  = threadIdx.x;
    const int lane = tid & 63;
    const int w    = __builtin_amdgcn_readfirstlane(tid >> 6);
    const int bx   = blockIdx.x;            // 0..KB-1
    const int by   = blockIdx.y;            // 0..37
    const int ib   = by >> 1;
    const int ioff = (by & 1) * 128 + lane * 2;

    int jlo = bx * CHUNK;
    int jhi = jlo + CHUNK; if (jhi > N_TH) jhi = N_TH;
    int span = jhi - jlo;
    int jw0 = jlo + (span * w) / 4;
    int jw1 = jlo + (span * (w + 1)) / 4;

    float acc[2][11];
#pragma unroll
    for (int r = 0; r < 2; r++)
#pragma unroll
        for (int c = 0; c < 11; c++) acc[r][c] = 0.f;

    const unsigned short* ap = A2 + (size_t)ib * N_TH * 256 + ioff;

    float pc[11];
#pragma unroll
    for (int c = 0; c < 11; c++) pc[c] = Prow[(size_t)jw0 * PRS + c];

    for (int j = jw0; j < jw1; ++j) {
        int jn = (j + 1 < jw1) ? j + 1 : jw1 - 1;
        float pn[11];
#pragma unroll
        for (int c = 0; c < 11; c++) pn[c] = Prow[(size_t)jn * PRS + c];

        unsigned int av = *reinterpret_cast<const unsigned int*>(ap + (size_t)j * 256);
        float a0 = __uint_as_float(av << 16);
        float a1 = __uint_as_float(av & 0xffff0000u);
#pragma unroll
        for (int c = 0; c < 11; c++) {
            acc[0][c] = fmaf(a0, pc[c], acc[0][c]);
            acc[1][c] = fmaf(a1, pc[c], acc[1][c]);
        }
#pragma unroll
        for (int c = 0; c < 11; c++) pc[c] = pn[c];
    }

    if (w > 0) {
#pragma unroll
        for (int r = 0; r < 2; r++)
#pragma unroll
            for (int c = 0; c < 11; c++)
                red[((w - 1) * 22 + r * 11 + c) * 64 + lane] = acc[r][c];
    }
    __syncthreads();
    if (w == 0) {
#pragma unroll
        for (int r = 0; r < 2; r++)
#pragma unroll
            for (int c = 0; c < 11; c++) {
                int s = (r * 11 + c) * 64 + lane;
                acc[r][c] += red[s] + red[22 * 64 + s] + red[44 * 64 + s];
            }
        const int i0 = by * 128 + lane * 2;
#pragma unroll
        for (int c = 0; c < 11; c++) {
            float2 v = make_float2(acc[0][c], acc[1][c]);
            *reinterpret_cast<float2*>(part + ((size_t)bx * 11 + c) * NPAD + i0) = v;
        }
    }
}

// ---------------------------------------------------------------------------
// Tier B step: reads fp32 A directly. grid (KB, 19); block owns 256 i rows.
// Stages A tile 256i x 32j into LDS transposed; each thread owns one i.
__global__ __launch_bounds__(256) void k_stepB(const float* __restrict__ A,
                                               const float* __restrict__ Prow,
                                               float* __restrict__ part) {
    __shared__ float As[32 * 261];
    const int tid = threadIdx.x;
    const int bx = blockIdx.x;     // 0..KB-1
    const int by = blockIdx.y;     // 0..18
    const int i0 = by * 256;
    const int jlo = bx * CHUNK;
    int jhi = jlo + CHUNK; if (jhi > N_TH) jhi = N_TH;

    float acc[11];
#pragma unroll
    for (int c = 0; c < 11; c++) acc[c] = 0.f;

    for (int j0 = jlo; j0 < jhi; j0 += 32) {
        int jn = jhi - j0; if (jn > 32) jn = 32;
#pragma unroll
        for (int s = 0; s < 32; s++) {
            int idx = s * 256 + tid;
            int r = idx >> 5, jj = idx & 31;
            int ii = i0 + r, j = j0 + jj;
            float v = 0.f;
            if (jj < jn && ii < N_TH) {
                v = A[(size_t)ii * N_TH + j];
                if (ii == j) v -= 1.f;
            }
            As[jj * 261 + r] = v;
        }
        __syncthreads();
        if (jn == 32) {
#pragma unroll
            for (int jj = 0; jj < 32; jj++) {
                float a = As[jj * 261 + tid];
                const float* pr = Prow + (size_t)(j0 + jj) * PRS;
#pragma unroll
                for (int c = 0; c < 11; c++) acc[c] = fmaf(a, pr[c], acc[c]);
            }
        } else {
            for (int jj = 0; jj < jn; jj++) {
                float a = As[jj * 261 + tid];
                const float* pr = Prow + (size_t)(j0 + jj) * PRS;
#pragma unroll
                for (int c = 0; c < 11; c++) acc[c] = fmaf(a, pr[c], acc[c]);
            }
        }
        __syncthreads();
    }
#pragma unroll
    for (int c = 0; c < 11; c++)
        part[((size_t)bx * 11 + c) * NPAD + i0 + tid] = acc[c];
}

// ---------------------------------------------------------------------------
// P_k[i][c] = P_{k-1}[i][c] + sum_s part[s][c][i]; in-place Prow update;
// packed PcolX: col0 -> kplane k-1 cc0 (bias of step k); cols1..10 -> kplane k.
__global__ __launch_bounds__(256) void k_reduce(const float* __restrict__ part,
                                                float* __restrict__ Prow,
                                                float* __restrict__ PcolX,
                                                int k) {
    int t = blockIdx.x * 256 + threadIdx.x;   // over 11*NPAD
    if (t >= 11 * NPAD) return;
    int c = t / NPAD, i = t - c * NPAD;
    float s = Prow[(size_t)i * PRS + c];
#pragma unroll 8
    for (int sl = 0; sl < KB; sl++)
        s += part[((size_t)sl * 11 + c) * NPAD + i];
    Prow[(size_t)i * PRS + c] = s;
    if (i < PCS) {
        if (c == 0)       PcolX[((size_t)(k - 1) * 11) * PCS + i] = s;
        else if (k <= 31) PcolX[((size_t)k * 11 + c) * PCS + i] = s;
    }
}

// ---------------------------------------------------------------------------
// theta[bt][i] = bias + sum_{j<t,d} P_j[1+d][i] * du[b][t-j][d]
// GEMM M=1024, N=4609, K=320. Tile 64 bt x 128 i; thread 8x4. grid (37,16).
__global__ __launch_bounds__(256) void k_conv(const float* __restrict__ du,
                                              const float* __restrict__ PcolX,
                                              float* __restrict__ theta) {
    __shared__ float CfT[32][72];
    __shared__ float Pl[32][132];
    const int tid = threadIdx.x;
    const int tn = tid & 31, tm = tid >> 5;
    const int i0  = blockIdx.x * 128;
    const int bt0 = blockIdx.y * 64;

    float acc[8][4];
#pragma unroll
    for (int r = 0; r < 8; r++)
#pragma unroll
        for (int n = 0; n < 4; n++) acc[r][n] = 0.f;

    for (int k0 = 0; k0 < 320; k0 += 32) {
#pragma unroll
        for (int s = 0; s < 8; s++) {
            int idx = s * 256 + tid;
            int kk = idx >> 6, m = idx & 63;
            int k = k0 + kk;
            int j = k / 10, d = k - j * 10;
            int bt = bt0 + m, t = bt & 31, b = bt >> 5;
            float v = 0.f;
            if (j < t) v = du[(size_t)(b * NL + (t - j)) * IND + d];
            CfT[kk][m] = v;
        }
#pragma unroll
        for (int s = 0; s < 16; s++) {
            int idx = s * 256 + tid;
            int kk = idx >> 7, ii = idx & 127;
            int k = k0 + kk;
            int j = k / 10, d = k - j * 10;
            int ig = i0 + ii;
            Pl[kk][ii] = (ig < N_TH) ? PcolX[((size_t)j * 11 + 1 + d) * PCS + ig] : 0.f;
        }
        __syncthreads();
#pragma unroll
        for (int kk = 0; kk < 32; kk++) {
            float4 a0 = *(const float4*)&CfT[kk][tm * 8];
            float4 a1 = *(const float4*)&CfT[kk][tm * 8 + 4];
            float4 bv = *(const float4*)&Pl[kk][tn * 4];
            acc[0][0] = fmaf(a0.x, bv.x, acc[0][0]);
            acc[0][1] = fmaf(a0.x, bv.y, acc[0][1]);
            acc[0][2] = fmaf(a0.x, bv.z, acc[0][2]);
            acc[0][3] = fmaf(a0.x, bv.w, acc[0][3]);
            acc[1][0] = fmaf(a0.y, bv.x, acc[1][0]);
            acc[1][1] = fmaf(a0.y, bv.y, acc[1][1]);
            acc[1][2] = fmaf(a0.y, bv.z, acc[1][2]);
            acc[1][3] = fmaf(a0.y, bv.w, acc[1][3]);
            acc[2][0] = fmaf(a0.z, bv.x, acc[2][0]);
            acc[2][1] = fmaf(a0.z, bv.y, acc[2][1]);
            acc[2][2] = fmaf(a0.z, bv.z, acc[2][2]);
            acc[2][3] = fmaf(a0.z, bv.w, acc[2][3]);
            acc[3][0] = fmaf(a0.w, bv.x, acc[3][0]);
            acc[3][1] = fmaf(a0.w, bv.y, acc[3][1]);
            acc[3][2] = fmaf(a0.w, bv.z, acc[3][2]);
            acc[3][3] = fmaf(a0.w, bv.w, acc[3][3]);
            acc[4][0] = fmaf(a1.x, bv.x, acc[4][0]);
            acc[4][1] = fmaf(a1.x, bv.y, acc[4][1]);
            acc[4][2] = fmaf(a1.x, bv.z, acc[4][2]);
            acc[4][3] = fmaf(a1.x, bv.w, acc[4][3]);
            acc[5][0] = fmaf(a1.y, bv.x, acc[5][0]);
            acc[5][1] = fmaf(a1.y, bv.y, acc[5][1]);
            acc[5][2] = fmaf(a1.y, bv.z, acc[5][2]);
            acc[5][3] = fmaf(a1.y, bv.w, acc[5][3]);
            acc[6][0] = fmaf(a1.z, bv.x, acc[6][0]);
            acc[6][1] = fmaf(a1.z, bv.y, acc[6][1]);
            acc[6][2] = fmaf(a1.z, bv.z, acc[6][2]);
            acc[6][3] = fmaf(a1.z, bv.w, acc[6][3]);
            acc[7][0] = fmaf(a1.w, bv.x, acc[7][0]);
            acc[7][1] = fmaf(a1.w, bv.y, acc[7][1]);
            acc[7][2] = fmaf(a1.w, bv.z, acc[7][2]);
            acc[7][3] = fmaf(a1.w, bv.w, acc[7][3]);
        }
        __syncthreads();
    }

#pragma unroll
    for (int r = 0; r < 8; r++) {
        int bt = bt0 + tm * 8 + r;
        int t = bt & 31;
        int i = i0 + tn * 4;
        float4 bb = *(const float4*)(PcolX + ((size_t)t * 11) * PCS + i);
        float4 o;
        o.x = acc[r][0] + bb.x;
        o.y = acc[r][1] + bb.y;
        o.z = acc[r][2] + bb.z;
        o.w = acc[r][3] + bb.w;
        float* dst = theta + (size_t)bt * TSTR + i;
        if (i + 3 < N_TH) {
            *(float4*)dst = o;
        } else {
            float ov[4] = {o.x, o.y, o.z, o.w};
#pragma unroll
            for (int e = 0; e < 4; e++)
                if (i + e < N_TH) dst[e] = ov[e];
        }
    }
}

// ---------------------------------------------------------------------------
__global__ __launch_bounds__(256) void k_mlp(const float* __restrict__ xs,
                                             const float* __restrict__ ts,
                                             const float* __restrict__ theta,
                                             float* __restrict__ out) {
    const int tid  = threadIdx.x;
    const int lane = tid & 63;
    const int half = (lane >> 5) & 1;
    const int o    = lane & 31;
    const int wv   = tid >> 6;
    const int bt   = blockIdx.x * 8 + wv * 2 + half;
    const int b = bt >> 5, t = bt & 31;
    const float* th = theta + (size_t)bt * TSTR;

    float u[10];
    u[0] = ts[b * NL + t];
#pragma unroll
    for (int d = 0; d < 9; d++) u[1 + d] = xs[(b * NL + t) * 9 + d];

    float acc = th[320 + o];
#pragma unroll
    for (int i = 0; i < 10; i++) acc = fmaf(th[o * 10 + i], u[i], acc);
    float h = fmaxf(acc, 0.f);

#pragma unroll
    for (int l = 0; l < 4; l++) {
        int base = 352 + l * 1056;
        float a2 = th[base + 1024 + o];
#pragma unroll
        for (int i = 0; i < 32; i++)
            a2 = fmaf(th[base + o * 32 + i], __shfl(h, i, 32), a2);
        h = fmaxf(a2, 0.f);
    }

    float contrib = th[4576 + o] * h;
#pragma unroll
    for (int m = 16; m >= 1; m >>= 1) contrib += __shfl_xor(contrib, m, 32);
    if (o == 0) out[bt] = contrib + th[4608];
}

// ---------------------------------------------------------------------------
extern "C" void kernel_launch(void* const* d_in, const int* in_sizes, int n_in,
                              void* d_out, int out_size, void* d_ws, size_t ws_size,
                              hipStream_t stream) {
    const float* xs  = (const float*)d_in[0];
    const float* ts  = (const float*)d_in[1];
    const float* A   = (const float*)d_in[2];
    const float* Bm  = (const float*)d_in[3];
    const float* th0 = (const float*)d_in[4];
    float* out = (float*)d_out;
    float* ws  = (float*)d_ws;

    const bool tierA = ws_size >= TIER_A_FLOATS * 4ULL;

    float* du     = ws + OF_DU;
    float* Prow   = ws + OF_PROW;
    float* PcolX  = ws + OF_PCOL;
    float* part   = ws + OF_PART;
    unsigned short* A2 = (unsigned short*)(ws + OF_A2);
    float* theta  = tierA ? (ws + OF_A2) : (ws + OF_PART);  // alias dead region

    k_du<<<40, 256, 0, stream>>>(xs, ts, du);
    k_p0<<<228, 256, 0, stream>>>(th0, Bm, Prow, PcolX);
    if (tierA) k_tr<<<dim3(76, 73), 256, 0, stream>>>(A, A2);

    for (int k = 1; k <= 32; k++) {
        if (tierA) k_stepA<<<dim3(KB, 38), 256, 0, stream>>>(A2, Prow, part);
        else       k_stepB<<<dim3(KB, 19), 256, 0, stream>>>(A,  Prow, part);
        k_reduce<<<209, 256, 0, stream>>>(part, Prow, PcolX, k);
    }

    k_conv<<<dim3(37, 16), 256, 0, stream>>>(du, PcolX, theta);
    k_mlp<<<128, 256, 0, stream>>>(xs, ts, theta, out);
}

// Round 5
// 1098.359 us; speedup vs baseline: 1.1790x; 1.1290x over previous
//
#include <hip/hip_runtime.h>

// Problem constants
#define N_TH   4609      // D_THETA
#define A2W    4864      // A2p row width (dwords), padded i
#define NJP    2305      // number of j-pairs (ceil(4610/2))
#define PRS    12        // Prow row stride (floats)
#define PRWN   4612      // Prow rows
#define PCS    4612      // PcolX plane/col stride (floats)
#define TSTR   4612      // theta row stride (floats)
#define NB     32
#define NL     32
#define IND    10

// ws layout (float offsets). part sized by runtime KB; A2p follows part.
#define OF_DU    0          // 10,240
#define OF_PROW  10240      // 4612*12 = 55,344 -> end 65,584
#define OF_PCOL  65584      // 32*11*4612 = 1,623,424 -> end 1,689,008
#define OF_PART  1689008    // KB*11*4864
// A2p: 2305*4864 = 11,211,520 fl (44.85 MB)
// totals: KB=32 -> 58,450,624 B ; KB=16 -> 55,026,368 B (<= proven-safe 55,027,712)
#define NEED_KB32 58450624ULL

// ---------------------------------------------------------------------------
__global__ __launch_bounds__(256) void k_du(const float* __restrict__ xs,
                                            const float* __restrict__ ts,
                                            float* __restrict__ du) {
    int idx = blockIdx.x * 256 + threadIdx.x;
    if (idx >= NB * NL * IND) return;
    int d  = idx % IND;
    int bt = idx / IND;
    int t = bt % NL, b = bt / NL;
    if (t == 0) { du[idx] = 0.f; return; }
    float cur  = (d == 0) ? ts[b * NL + t]     : xs[(b * NL + t) * 9 + (d - 1)];
    float prev = (d == 0) ? ts[b * NL + t - 1] : xs[(b * NL + t - 1) * 9 + (d - 1)];
    du[idx] = cur - prev;
}

// ---------------------------------------------------------------------------
// P_0 = [theta0 | B] into Prow (4612 rows, stride 12, zero-padded) and PcolX
// kplane 0 cols 1..10.
__global__ __launch_bounds__(256) void k_p0(const float* __restrict__ th0,
                                            const float* __restrict__ Bm,
                                            float* __restrict__ Prow,
                                            float* __restrict__ PcolX) {
    int idx = blockIdx.x * 256 + threadIdx.x;   // over PRWN*12
    if (idx >= PRWN * PRS) return;
    int i = idx / PRS, c = idx - i * PRS;
    float v = 0.f;
    if (i < N_TH) {
        if (c == 0) v = th0[i];
        else if (c <= 10) v = Bm[(size_t)i * 10 + (c - 1)];
    }
    Prow[idx] = v;
    if (c >= 1 && c <= 10)
        PcolX[(size_t)c * PCS + i] = v;   // kplane 0, col c
}

// ---------------------------------------------------------------------------
// Transpose+convert+pack: A2p[jp*4864 + i] = bf16(A[i][2jp]-d) | bf16(A[i][2jp+1]-d)<<16
// 64x64 tiles via LDS. grid (76 i-tiles, 73 j-tiles).
__global__ __launch_bounds__(256) void k_tr(const float* __restrict__ A,
                                            unsigned int* __restrict__ A2p) {
    __shared__ float T[64][65];
    const int tid = threadIdx.x;
    const int i0 = blockIdx.x * 64;   // 0..75
    const int j0 = blockIdx.y * 64;   // 0..72  (covers j < 4672)
#pragma unroll
    for (int e = 0; e < 16; e++) {
        int idx = e * 256 + tid;
        int r = idx >> 6, q = idx & 63;
        int i = i0 + r, j = j0 + q;
        float v = 0.f;
        if (i < N_TH && j < N_TH) {
            v = A[(size_t)i * N_TH + j];
            if (i == j) v -= 1.f;
        }
        T[r][q] = v;
    }
    __syncthreads();
#pragma unroll
    for (int e = 0; e < 8; e++) {
        int idx = e * 256 + tid;
        int jj2 = idx >> 6;           // 0..31 (jpair within tile)
        int ii  = idx & 63;
        int jp_g = (j0 >> 1) + jj2;
        if (jp_g < NJP) {
            float v0 = T[ii][jj2 * 2];
            float v1 = T[ii][jj2 * 2 + 1];
            unsigned int u0 = __float_as_uint(v0);
            unsigned int u1 = __float_as_uint(v1);
            unsigned int r0 = (u0 + 0x7fffu + ((u0 >> 16) & 1u)) >> 16;  // RNE
            unsigned int r1 = (u1 + 0x7fffu + ((u1 >> 16) & 1u)) >> 16;
            A2p[(size_t)jp_g * A2W + i0 + ii] = r0 | (r1 << 16);
        }
    }
}

// ---------------------------------------------------------------------------
// Step: part[bx][c][i] = sum_{jp in chunk bx} unpack2(A2p[jp][i]) . P[2jp..2jp+1][c]
// grid (KB, 19). Thread owns output row i = by*256+tid (no cross-lane reduce).
// Chunk's P rows staged in LDS once; inner loop: 1 prefetched global dword +
// 6 broadcast ds_read_b128 + 22 FMA.
__global__ __launch_bounds__(256) void k_stepC(const unsigned int* __restrict__ A2p,
                                               const float* __restrict__ Prow,
                                               float* __restrict__ part,
                                               int jchunk) {
    __shared__ float Pl[290 * 12];
    const int tid = threadIdx.x;
    const int bx = blockIdx.x;
    const int jlo = bx * jchunk;
    int jn = NJP - jlo; if (jn > jchunk) jn = jchunk;
    const int i = blockIdx.y * 256 + tid;

    // stage P rows [2*jlo, 2*(jlo+jn)) -> LDS (rows padded to 12 floats)
    const int nfl = 2 * jn * PRS;
    const float* src = Prow + (size_t)(2 * jlo) * PRS;
    for (int s = tid; s < nfl; s += 256) Pl[s] = src[s];
    __syncthreads();

    float acc[11];
#pragma unroll
    for (int c = 0; c < 11; c++) acc[c] = 0.f;

    const unsigned int* ap = A2p + (size_t)jlo * A2W + i;
    unsigned int av = ap[0];
#pragma unroll 4
    for (int q = 0; q < jn; ++q) {
        unsigned int avc = av;
        if (q + 1 < jn) av = ap[(size_t)(q + 1) * A2W];
        float a0 = __uint_as_float(avc << 16);
        float a1 = __uint_as_float(avc & 0xffff0000u);
        const float* pr = &Pl[q * 24];
        float4 p0a = *(const float4*)(pr);
        float4 p0b = *(const float4*)(pr + 4);
        float4 p0c = *(const float4*)(pr + 8);
        float4 p1a = *(const float4*)(pr + 12);
        float4 p1b = *(const float4*)(pr + 16);
        float4 p1c = *(const float4*)(pr + 20);
        acc[0]  = fmaf(a0, p0a.x, acc[0]);
        acc[1]  = fmaf(a0, p0a.y, acc[1]);
        acc[2]  = fmaf(a0, p0a.z, acc[2]);
        acc[3]  = fmaf(a0, p0a.w, acc[3]);
        acc[4]  = fmaf(a0, p0b.x, acc[4]);
        acc[5]  = fmaf(a0, p0b.y, acc[5]);
        acc[6]  = fmaf(a0, p0b.z, acc[6]);
        acc[7]  = fmaf(a0, p0b.w, acc[7]);
        acc[8]  = fmaf(a0, p0c.x, acc[8]);
        acc[9]  = fmaf(a0, p0c.y, acc[9]);
        acc[10] = fmaf(a0, p0c.z, acc[10]);
        acc[0]  = fmaf(a1, p1a.x, acc[0]);
        acc[1]  = fmaf(a1, p1a.y, acc[1]);
        acc[2]  = fmaf(a1, p1a.z, acc[2]);
        acc[3]  = fmaf(a1, p1a.w, acc[3]);
        acc[4]  = fmaf(a1, p1b.x, acc[4]);
        acc[5]  = fmaf(a1, p1b.y, acc[5]);
        acc[6]  = fmaf(a1, p1b.z, acc[6]);
        acc[7]  = fmaf(a1, p1b.w, acc[7]);
        acc[8]  = fmaf(a1, p1c.x, acc[8]);
        acc[9]  = fmaf(a1, p1c.y, acc[9]);
        acc[10] = fmaf(a1, p1c.z, acc[10]);
    }

#pragma unroll
    for (int c = 0; c < 11; c++)
        part[((size_t)bx * 11 + c) * A2W + i] = acc[c];
}

// ---------------------------------------------------------------------------
// P_k[i][c] = P_{k-1}[i][c] + sum_s part[s][c][i]; in-place Prow update;
// packed PcolX: c0 -> kplane k-1 col0 (bias for t=k-1); c1..10 -> kplane k (k<=31).
__global__ __launch_bounds__(256) void k_reduce(const float* __restrict__ part,
                                                float* __restrict__ Prow,
                                                float* __restrict__ PcolX,
                                                int k, int kb) {
    int t = blockIdx.x * 256 + threadIdx.x;   // over 11*PRWN
    if (t >= 11 * PRWN) return;
    int c = t / PRWN, i = t - c * PRWN;
    float s = Prow[(size_t)i * PRS + c];
#pragma unroll 4
    for (int sl = 0; sl < kb; sl++)
        s += part[((size_t)sl * 11 + c) * A2W + i];
    Prow[(size_t)i * PRS + c] = s;
    if (c == 0)       PcolX[((size_t)(k - 1) * 11) * PCS + i] = s;
    else if (k <= 31) PcolX[((size_t)k * 11 + c) * PCS + i] = s;
}

// ---------------------------------------------------------------------------
// theta[bt][i] = bias + sum_{j<t,d} P_j[1+d][i] * du[b][t-j][d]
// GEMM M=1024, N=4609, K=320. Tile 32 bt x 128 i; thread 4x4. grid (37,32).
__global__ __launch_bounds__(256) void k_conv(const float* __restrict__ du,
                                              const float* __restrict__ PcolX,
                                              float* __restrict__ theta) {
    __shared__ float CfT[32][36];    // [kk][m]
    __shared__ float Pl[32][132];    // [kk][ii]
    const int tid = threadIdx.x;
    const int tn = tid & 31, tm = tid >> 5;   // tn: i-group (32), tm: bt-group (8)
    const int i0  = blockIdx.x * 128;
    const int bt0 = blockIdx.y * 32;

    float acc[4][4];
#pragma unroll
    for (int r = 0; r < 4; r++)
#pragma unroll
        for (int n = 0; n < 4; n++) acc[r][n] = 0.f;

    for (int k0 = 0; k0 < 320; k0 += 32) {
#pragma unroll
        for (int s = 0; s < 4; s++) {
            int idx = s * 256 + tid;
            int m = idx >> 5, kk = idx & 31;
            int k = k0 + kk;
            int j = k / 10, d = k - j * 10;
            int bt = bt0 + m, t = bt & 31, b = bt >> 5;
            float v = 0.f;
            if (j < t) v = du[(size_t)(b * NL + (t - j)) * IND + d];
            CfT[kk][m] = v;
        }
#pragma unroll
        for (int s = 0; s < 16; s++) {
            int idx = s * 256 + tid;
            int kk = idx >> 7, ii = idx & 127;
            int k = k0 + kk;
            int j = k / 10, d = k - j * 10;
            int ig = i0 + ii;
            Pl[kk][ii] = (ig < N_TH) ? PcolX[((size_t)j * 11 + 1 + d) * PCS + ig] : 0.f;
        }
        __syncthreads();
#pragma unroll
        for (int kk = 0; kk < 32; kk++) {
            float4 a = *(const float4*)&CfT[kk][tm * 4];
            float4 bv = *(const float4*)&Pl[kk][tn * 4];
            acc[0][0] = fmaf(a.x, bv.x, acc[0][0]);
            acc[0][1] = fmaf(a.x, bv.y, acc[0][1]);
            acc[0][2] = fmaf(a.x, bv.z, acc[0][2]);
            acc[0][3] = fmaf(a.x, bv.w, acc[0][3]);
            acc[1][0] = fmaf(a.y, bv.x, acc[1][0]);
            acc[1][1] = fmaf(a.y, bv.y, acc[1][1]);
            acc[1][2] = fmaf(a.y, bv.z, acc[1][2]);
            acc[1][3] = fmaf(a.y, bv.w, acc[1][3]);
            acc[2][0] = fmaf(a.z, bv.x, acc[2][0]);
            acc[2][1] = fmaf(a.z, bv.y, acc[2][1]);
            acc[2][2] = fmaf(a.z, bv.z, acc[2][2]);
            acc[2][3] = fmaf(a.z, bv.w, acc[2][3]);
            acc[3][0] = fmaf(a.w, bv.x, acc[3][0]);
            acc[3][1] = fmaf(a.w, bv.y, acc[3][1]);
            acc[3][2] = fmaf(a.w, bv.z, acc[3][2]);
            acc[3][3] = fmaf(a.w, bv.w, acc[3][3]);
        }
        __syncthreads();
    }

#pragma unroll
    for (int r = 0; r < 4; r++) {
        int bt = bt0 + tm * 4 + r;
        int t = bt & 31;
        int i = i0 + tn * 4;
        float4 bb = *(const float4*)(PcolX + ((size_t)t * 11) * PCS + i);
        float4 o;
        o.x = acc[r][0] + bb.x;
        o.y = acc[r][1] + bb.y;
        o.z = acc[r][2] + bb.z;
        o.w = acc[r][3] + bb.w;
        float* dst = theta + (size_t)bt * TSTR + i;
        if (i + 3 < N_TH) {
            *(float4*)dst = o;
        } else {
            float ov[4] = {o.x, o.y, o.z, o.w};
#pragma unroll
            for (int e = 0; e < 4; e++)
                if (i + e < N_TH) dst[e] = ov[e];
        }
    }
}

// ---------------------------------------------------------------------------
__global__ __launch_bounds__(256) void k_mlp(const float* __restrict__ xs,
                                             const float* __restrict__ ts,
                                             const float* __restrict__ theta,
                                             float* __restrict__ out) {
    const int tid  = threadIdx.x;
    const int lane = tid & 63;
    const int half = (lane >> 5) & 1;
    const int o    = lane & 31;
    const int wv   = tid >> 6;
    const int bt   = blockIdx.x * 8 + wv * 2 + half;
    const int b = bt >> 5, t = bt & 31;
    const float* th = theta + (size_t)bt * TSTR;

    float u[10];
    u[0] = ts[b * NL + t];
#pragma unroll
    for (int d = 0; d < 9; d++) u[1 + d] = xs[(b * NL + t) * 9 + d];

    float acc = th[320 + o];
#pragma unroll
    for (int i = 0; i < 10; i++) acc = fmaf(th[o * 10 + i], u[i], acc);
    float h = fmaxf(acc, 0.f);

#pragma unroll
    for (int l = 0; l < 4; l++) {
        int base = 352 + l * 1056;
        float a2 = th[base + 1024 + o];
#pragma unroll
        for (int i = 0; i < 32; i++)
            a2 = fmaf(th[base + o * 32 + i], __shfl(h, i, 32), a2);
        h = fmaxf(a2, 0.f);
    }

    float contrib = th[4576 + o] * h;
#pragma unroll
    for (int m = 16; m >= 1; m >>= 1) contrib += __shfl_xor(contrib, m, 32);
    if (o == 0) out[bt] = contrib + th[4608];
}

// ---------------------------------------------------------------------------
extern "C" void kernel_launch(void* const* d_in, const int* in_sizes, int n_in,
                              void* d_out, int out_size, void* d_ws, size_t ws_size,
                              hipStream_t stream) {
    const float* xs  = (const float*)d_in[0];
    const float* ts  = (const float*)d_in[1];
    const float* A   = (const float*)d_in[2];
    const float* Bm  = (const float*)d_in[3];
    const float* th0 = (const float*)d_in[4];
    float* out = (float*)d_out;
    float* ws  = (float*)d_ws;

    const int KBv = (ws_size >= NEED_KB32) ? 32 : 16;
    const int jchunk = (NJP + KBv - 1) / KBv;   // 73 or 145

    float* du    = ws + OF_DU;
    float* Prow  = ws + OF_PROW;
    float* PcolX = ws + OF_PCOL;
    float* part  = ws + OF_PART;
    unsigned int* A2p = (unsigned int*)(ws + OF_PART + (size_t)KBv * 11 * A2W);
    float* theta = (float*)A2p;   // aliases A2p (dead after steps)

    k_du<<<40, 256, 0, stream>>>(xs, ts, du);
    k_p0<<<217, 256, 0, stream>>>(th0, Bm, Prow, PcolX);
    k_tr<<<dim3(76, 73), 256, 0, stream>>>(A, A2p);

    for (int k = 1; k <= 32; k++) {
        k_stepC<<<dim3(KBv, 19), 256, 0, stream>>>(A2p, Prow, part, jchunk);
        k_reduce<<<199, 256, 0, stream>>>(part, Prow, PcolX, k, KBv);
    }

    k_conv<<<dim3(37, 32), 256, 0, stream>>>(du, PcolX, theta);
    k_mlp<<<128, 256, 0, stream>>>(xs, ts, theta, out);
}